// Round 6
// baseline (76.637 us; speedup 1.0000x reference)
//
#include <hip/hip_runtime.h>

typedef __bf16 bf16_t;
typedef bf16_t bf16x8 __attribute__((ext_vector_type(8)));
typedef float f32x4 __attribute__((ext_vector_type(4)));

#define Bsz 4096   // batch rows (M)
#define Csz 4096   // centers (N)
#define Dsz 1024   // data dim (K)
#define BM 128
#define BN 128
#define BK 32
#define NT (Dsz/BK)         // 32 K-tiles
#define NPC 64              // partial column-groups: 32 bn-tiles x 2 wc

// RNE f32 -> bf16 bits
__device__ inline unsigned short f2bf(float f){
  unsigned u = __float_as_uint(f);
  u += 0x7FFFu + ((u >> 16) & 1u);
  return (unsigned short)(u >> 16);
}

// inline-asm LDS read: opaque to alias analysis, so the compiler cannot
// insert vmcnt(0) drains against the global_load_lds prefetch queue.
__device__ __forceinline__ bf16x8 dsr128(unsigned byte_off){
  bf16x8 r;
  asm volatile("ds_read_b128 %0, %1" : "=v"(r) : "v"(byte_off));
  return r;
}

// ---------------- prep: x2/c2 (f32 exact) + bf16 conversion ----------------
__global__ __launch_bounds__(256) void prep_kernel(
    const float* __restrict__ x, const float* __restrict__ cen,
    unsigned short* __restrict__ xb, unsigned short* __restrict__ cb,
    float* __restrict__ x2, float* __restrict__ c2)
{
  int w = blockIdx.x * 4 + (threadIdx.x >> 6);   // global wave id, one row each
  int lane = threadIdx.x & 63;
  const float* src; unsigned short* dst; float* sq; int row;
  if (w < Bsz) { row = w;       src = x;   dst = xb; sq = x2; }
  else         { row = w - Bsz; src = cen; dst = cb; sq = c2; }

  const float4* s4 = (const float4*)(src + (size_t)row * Dsz);
  unsigned short* d = dst + (size_t)row * Dsz;
  float ss = 0.f;
  #pragma unroll
  for (int t = 0; t < 4; ++t){
    float4 v = s4[t * 64 + lane];
    ss += v.x*v.x + v.y*v.y + v.z*v.z + v.w*v.w;
    ushort4 u; u.x = f2bf(v.x); u.y = f2bf(v.y); u.z = f2bf(v.z); u.w = f2bf(v.w);
    *(ushort4*)(d + (size_t)(t * 64 + lane) * 4) = u;
  }
  #pragma unroll
  for (int off = 32; off >= 1; off >>= 1) ss += __shfl_xor(ss, off, 64);
  if (lane == 0) sq[row] = ss;
}

// ------- 128x128 3-block/CU, 3-deep-ring fused GEMM + RBF epilogue -------
// 256 thr = 4 waves (2 wr x 2 wc). Per wave: 64x64 output = 4x4 frags 16x16.
// BK=32; LDS ring of 3 bufs x (A 128x32 + B 128x32) bf16 = 48 KiB ->
// 3 blocks/CU resident (12 waves/CU). Swizzle: LDS[r][c16]=G[r][c16^((r>>1)&3)]
// (linear gload_lds dest, pre-swizzled source, same XOR on read).
// Per tile: ds_reads(t) | stage(t+2) -> lgkm0 -> 16 MFMA -> vmcnt(4) -> barrier.
// vmcnt(4): waits stage(t+1) only; stage(t+2) stays in flight across the
// barrier with ~2 tiles of lead. Never drains to 0 until the tail.
__global__ __launch_bounds__(256, 3) void rbf_gemm_kernel(
    const unsigned short* __restrict__ xb, const unsigned short* __restrict__ cb,
    const float* __restrict__ x2, const float* __restrict__ c2,
    const float* __restrict__ beta, const float* __restrict__ W,
    float* __restrict__ partials)
{
  __shared__ __align__(16) unsigned short smem[24576];  // 48 KiB = 3 x 16 KiB

  const int tid  = threadIdx.x;
  const int wid  = tid >> 6;
  const int lane = tid & 63;
  const int wr   = wid >> 1;        // 0..1
  const int wc   = wid & 1;         // 0..1
  const int l15  = lane & 15;
  const int lhi  = lane >> 4;

  // XCD mapping: xcd = id%8; each XCD owns two 8x8 (bm,bn) rects -> ~4 MB
  // working set per XCD (= its L2). (R4: FETCH 37.5 -> 26 MB)
  const int id   = blockIdx.x;          // 0..1023
  const int xcd  = id & 7;
  const int jj   = id >> 3;             // 0..127
  const int rect = xcd + 8 * (jj >> 6); // 0..15
  const int pos  = jj & 63;             // 0..63
  const int bm   = (rect & 3) * 8 + (pos & 7);
  const int bn   = (rect >> 2) * 8 + (pos >> 3);

  const unsigned short* gA = xb + (size_t)(bm * BM) * Dsz;
  const unsigned short* gB = cb + (size_t)(bn * BN) * Dsz;

  // staging: one gload_lds = 64 lanes x 16B; rows have 4 chunks of 16B ->
  // 256 thr cover 64 rows/pass; 2 passes per 128-row panel; 4 calls/thread.
  const int srow = tid >> 2;                          // 0..63
  const int sc   = (tid & 3) ^ ((srow >> 1) & 3);     // pre-swizzled src chunk

  // read-side swizzled byte offsets: chunk = lhi ^ ((row>>1)&3), row=...+l15
  const unsigned lds_base =
      (unsigned)(uintptr_t)(__attribute__((address_space(3))) unsigned short*)smem;
  const unsigned xr   = (unsigned)((lhi ^ ((l15 >> 1) & 3)) * 16);
  const unsigned aoff = lds_base +          (unsigned)((wr * 64 + l15) * 64) + xr;
  const unsigned boff = lds_base + 8192u +  (unsigned)((wc * 64 + l15) * 64) + xr;

#define GLDS(GSRC, LUS) \
    __builtin_amdgcn_global_load_lds( \
      (const __attribute__((address_space(1))) unsigned int*)(GSRC), \
      (__attribute__((address_space(3))) unsigned int*)&smem[LUS], 16, 0, 0);

  // stage full tile KT into ring buf P (4 gload_lds per thread)
#define STAGE_T(P, KT) { \
    const unsigned short* ga_ = gA + (size_t)srow * Dsz + (KT)*BK + sc*8; \
    GLDS(ga_,                    (P)*8192 +        wid*512) \
    GLDS(ga_ + (size_t)64*Dsz,   (P)*8192 + 2048 + wid*512) \
    const unsigned short* gb_ = gB + (size_t)srow * Dsz + (KT)*BK + sc*8; \
    GLDS(gb_,                    (P)*8192 + 4096 + wid*512) \
    GLDS(gb_ + (size_t)64*Dsz,   (P)*8192 + 6144 + wid*512) }

  f32x4 acc[4][4];
  #pragma unroll
  for (int mi = 0; mi < 4; ++mi)
    #pragma unroll
    for (int ni = 0; ni < 4; ++ni)
      acc[mi][ni] = (f32x4){0.f, 0.f, 0.f, 0.f};

  bf16x8 av[4], bv[4];

#define LD_AB(P) { \
    _Pragma("unroll") \
    for (int mi_ = 0; mi_ < 4; ++mi_) av[mi_] = dsr128(aoff + (P)*16384u + mi_*1024u); \
    _Pragma("unroll") \
    for (int ni_ = 0; ni_ < 4; ++ni_) bv[ni_] = dsr128(boff + (P)*16384u + ni_*1024u); }

#define MFMA16 { \
    _Pragma("unroll") \
    for (int mi_ = 0; mi_ < 4; ++mi_) \
      _Pragma("unroll") \
      for (int ni_ = 0; ni_ < 4; ++ni_) \
        acc[mi_][ni_] = __builtin_amdgcn_mfma_f32_16x16x32_bf16(av[mi_], bv[ni_], acc[mi_][ni_], 0,0,0); }

  // tile body: reads(t) | stage(t+2) -> lgkm0 -> MFMA -> counted vmcnt -> barrier
#define TILE(T, P) { \
    LD_AB(P) \
    if ((T) + 2 < NT) STAGE_T(((P) + 2) % 3, (T) + 2) \
    asm volatile("s_waitcnt lgkmcnt(0)" ::: "memory"); \
    __builtin_amdgcn_sched_barrier(0); \
    __builtin_amdgcn_s_setprio(1); \
    MFMA16 \
    __builtin_amdgcn_s_setprio(0); \
    __builtin_amdgcn_sched_barrier(0); \
    if ((T) + 2 < NT) { asm volatile("s_waitcnt vmcnt(4)" ::: "memory"); } \
    else if ((T) + 1 < NT) { asm volatile("s_waitcnt vmcnt(0)" ::: "memory"); } \
    __builtin_amdgcn_sched_barrier(0); \
    __builtin_amdgcn_s_barrier(); }

  // Prologue: stage tiles 0,1 into bufs 0,1; wait tile0 (leave tile1 in flight).
  STAGE_T(0, 0)
  STAGE_T(1, 1)
  asm volatile("s_waitcnt vmcnt(4)" ::: "memory");
  __builtin_amdgcn_s_barrier();

  for (int tt = 0; tt < NT - 2; tt += 3){   // tt = 0,3,...,27 -> tiles 0..29
    TILE(tt,     0)
    TILE(tt + 1, 1)
    TILE(tt + 2, 2)
  }
  TILE(NT - 2, 0)   // tile 30, buf 30%3=0
  TILE(NT - 1, 1)   // tile 31, buf 31%3=1

  // ---- fused epilogue: d2 -> dist -> exp -> *W, then column-sum ----
  const int rowbase0 = bm * BM + wr * 64;
  f32x4 rs[4];
  #pragma unroll
  for (int mi = 0; mi < 4; ++mi) rs[mi] = (f32x4){0.f, 0.f, 0.f, 0.f};

  f32x4 x2r[4];
  #pragma unroll
  for (int mi = 0; mi < 4; ++mi)
    x2r[mi] = *(const f32x4*)&x2[rowbase0 + mi * 16 + lhi * 4];

  #pragma unroll
  for (int ni = 0; ni < 4; ++ni){
    const int col = bn * BN + wc * 64 + ni * 16 + l15;
    const float c2v = c2[col], bt = beta[col], wv = W[col];
    #pragma unroll
    for (int mi = 0; mi < 4; ++mi)
      #pragma unroll
      for (int j = 0; j < 4; ++j){
        float s    = acc[mi][ni][j];
        float d2   = x2r[mi][j] + c2v - 2.0f * s;
        float dist = sqrtf(fmaxf(d2, 0.0f));
        rs[mi][j] += wv * __expf(-bt * dist);   // exp(<=0) can't be inf
      }
  }

  // reduce over the 16 lanes holding different cols; write per-(bn,wc) partials
  const size_t pcbase = (size_t)(bn * 2 + wc) * Bsz;
  #pragma unroll
  for (int mi = 0; mi < 4; ++mi){
    #pragma unroll
    for (int j = 0; j < 4; ++j){
      float v = rs[mi][j];
      v += __shfl_xor(v, 1, 16);
      v += __shfl_xor(v, 2, 16);
      v += __shfl_xor(v, 4, 16);
      v += __shfl_xor(v, 8, 16);
      rs[mi][j] = v;
    }
    if (l15 == 0)
      *(f32x4*)&partials[pcbase + rowbase0 + mi * 16 + lhi * 4] = rs[mi];
  }
}

// ---------------- final reduction over column-groups ----------------
__global__ __launch_bounds__(256) void reduce_kernel(
    const float* __restrict__ partials, const float* __restrict__ bias,
    float* __restrict__ out)
{
  int b = blockIdx.x * 256 + threadIdx.x;
  float s = bias[0];
  #pragma unroll
  for (int t = 0; t < NPC; ++t) s += partials[(size_t)t * Bsz + b];
  out[b] = s;
}

// ---------------- naive f32 fallback (only if ws too small) ----------------
__global__ __launch_bounds__(256) void rbf_naive_kernel(
    const float* __restrict__ x, const float* __restrict__ cen,
    const float* __restrict__ beta, const float* __restrict__ W,
    const float* __restrict__ bias, float* __restrict__ out)
{
  __shared__ float4 xs4[Dsz / 4];
  __shared__ float red[256];
  int b = blockIdx.x;
  for (int i = threadIdx.x; i < Dsz / 4; i += 256)
    xs4[i] = ((const float4*)(x + (size_t)b * Dsz))[i];
  __syncthreads();
  float acc = 0.f;
  for (int j = threadIdx.x; j < Csz; j += 256){
    const float4* c4 = (const float4*)(cen + (size_t)j * Dsz);
    float d2 = 0.f;
    for (int k = 0; k < Dsz / 4; ++k){
      float4 cv = c4[k], xv = xs4[k];
      float a0 = xv.x - cv.x, a1 = xv.y - cv.y, a2 = xv.z - cv.z, a3 = xv.w - cv.w;
      d2 += a0*a0 + a1*a1 + a2*a2 + a3*a3;
    }
    acc += W[j] * expf(-beta[j] * sqrtf(fmaxf(d2, 0.f)));
  }
  red[threadIdx.x] = acc;
  __syncthreads();
  for (int s = 128; s >= 1; s >>= 1){
    if (threadIdx.x < s) red[threadIdx.x] += red[threadIdx.x + s];
    __syncthreads();
  }
  if (threadIdx.x == 0) out[b] = red[0] + bias[0];
}

extern "C" void kernel_launch(void* const* d_in, const int* in_sizes, int n_in,
                              void* d_out, int out_size, void* d_ws, size_t ws_size,
                              hipStream_t stream)
{
  const float* x    = (const float*)d_in[0];
  const float* cen  = (const float*)d_in[1];
  const float* beta = (const float*)d_in[2];
  const float* W    = (const float*)d_in[3];
  const float* bias = (const float*)d_in[4];
  float* out = (float*)d_out;

  const size_t off_xb = 0;
  const size_t off_cb = off_xb + (size_t)Bsz * Dsz * sizeof(unsigned short);
  const size_t off_x2 = off_cb + (size_t)Csz * Dsz * sizeof(unsigned short);
  const size_t off_c2 = off_x2 + (size_t)Bsz * sizeof(float);
  const size_t off_p  = off_c2 + (size_t)Csz * sizeof(float);
  const size_t need   = off_p  + (size_t)NPC * Bsz * sizeof(float);

  if (ws_size < need){
    rbf_naive_kernel<<<Bsz, 256, 0, stream>>>(x, cen, beta, W, bias, out);
    return;
  }

  char* ws = (char*)d_ws;
  unsigned short* xb = (unsigned short*)(ws + off_xb);
  unsigned short* cb = (unsigned short*)(ws + off_cb);
  float* x2 = (float*)(ws + off_x2);
  float* c2 = (float*)(ws + off_c2);
  float* pp = (float*)(ws + off_p);

  prep_kernel<<<(Bsz + Csz) / 4, 256, 0, stream>>>(x, cen, xb, cb, x2, c2);
  rbf_gemm_kernel<<<1024, 256, 0, stream>>>(xb, cb, x2, c2, beta, W, pp);
  reduce_kernel<<<Bsz / 256, 256, 0, stream>>>(pp, bias, out);
}

// Round 7
// 72.833 us; speedup vs baseline: 1.0522x; 1.0522x over previous
//
#include <hip/hip_runtime.h>

typedef __bf16 bf16_t;
typedef bf16_t bf16x8 __attribute__((ext_vector_type(8)));
typedef float f32x4 __attribute__((ext_vector_type(4)));

#define Bsz 4096   // batch rows (M)
#define Csz 4096   // centers (N)
#define Dsz 1024   // data dim (K)
#define BM 128
#define BN 128
#define BK 64
#define NT (Dsz/BK)         // 16 K-tiles
#define NPC 64              // partial column-groups: 32 bn-tiles x 2 wc

// RNE f32 -> bf16 bits
__device__ inline unsigned short f2bf(float f){
  unsigned u = __float_as_uint(f);
  u += 0x7FFFu + ((u >> 16) & 1u);
  return (unsigned short)(u >> 16);
}

// ---------------- prep: x2/c2 (f32 exact) + bf16 conversion ----------------
__global__ __launch_bounds__(256) void prep_kernel(
    const float* __restrict__ x, const float* __restrict__ cen,
    unsigned short* __restrict__ xb, unsigned short* __restrict__ cb,
    float* __restrict__ x2, float* __restrict__ c2)
{
  int w = blockIdx.x * 4 + (threadIdx.x >> 6);   // global wave id, one row each
  int lane = threadIdx.x & 63;
  const float* src; unsigned short* dst; float* sq; int row;
  if (w < Bsz) { row = w;       src = x;   dst = xb; sq = x2; }
  else         { row = w - Bsz; src = cen; dst = cb; sq = c2; }

  const float4* s4 = (const float4*)(src + (size_t)row * Dsz);
  unsigned short* d = dst + (size_t)row * Dsz;
  float ss = 0.f;
  #pragma unroll
  for (int t = 0; t < 4; ++t){
    float4 v = s4[t * 64 + lane];
    ss += v.x*v.x + v.y*v.y + v.z*v.z + v.w*v.w;
    ushort4 u; u.x = f2bf(v.x); u.y = f2bf(v.y); u.z = f2bf(v.z); u.w = f2bf(v.w);
    *(ushort4*)(d + (size_t)(t * 64 + lane) * 4) = u;
  }
  #pragma unroll
  for (int off = 32; off >= 1; off >>= 1) ss += __shfl_xor(ss, off, 64);
  if (lane == 0) sq[row] = ss;
}

// --------- m97-faithful 128x128 fused GEMM + RBF epilogue ---------
// 256 thr = 4 waves (2 wr x 2 wc). Per wave: 64x64 output = 4x4 frags 16x16.
// Single LDS buffer (A 128x64 + B 128x64 bf16 = 32 KiB) -> 4 blocks/CU.
// Loop per tile: stage(t) via 8x global_load_lds(16B) -> __syncthreads()
// (compiler drains vmcnt) -> kk=0,1 { plain C++ bf16x8 LDS reads + 16 MFMA,
// compiler emits ds_read_b128 with fine-grained lgkmcnt interleave } ->
// __syncthreads(). No inline asm in the loop: m97's compiler scheduling.
// Swizzle: LDS[r][c16] = G[r][c16 ^ (r&7)] (linear gload dest, pre-swizzled
// source, same XOR on read) -> 0 bank conflicts (measured R4/R5).
__global__ __launch_bounds__(256, 4) void rbf_gemm_kernel(
    const unsigned short* __restrict__ xb, const unsigned short* __restrict__ cb,
    const float* __restrict__ x2, const float* __restrict__ c2,
    const float* __restrict__ beta, const float* __restrict__ W,
    float* __restrict__ partials)
{
  __shared__ __align__(16) unsigned short As[BM * BK];  // 16 KiB
  __shared__ __align__(16) unsigned short Bs[BN * BK];  // 16 KiB

  const int tid  = threadIdx.x;
  const int wid  = tid >> 6;
  const int lane = tid & 63;
  const int wr   = wid >> 1;        // 0..1
  const int wc   = wid & 1;         // 0..1
  const int l15  = lane & 15;
  const int lhi  = lane >> 4;

  // XCD mapping: xcd = id%8; each XCD owns two 8x8 (bm,bn) rects -> ~4 MB
  // working set per XCD (= its L2). (R4: FETCH 37.5 -> 26 MB)
  const int id   = blockIdx.x;          // 0..1023
  const int xcd  = id & 7;
  const int jj   = id >> 3;             // 0..127
  const int rect = xcd + 8 * (jj >> 6); // 0..15
  const int pos  = jj & 63;             // 0..63
  const int bm   = (rect & 3) * 8 + (pos & 7);
  const int bn   = (rect >> 2) * 8 + (pos >> 3);

  const unsigned short* gA = xb + (size_t)(bm * BM) * Dsz;
  const unsigned short* gB = cb + (size_t)(bn * BN) * Dsz;

  // staging: one gload_lds = 64 lanes x 16B = 8 rows x 8 chunks; 256 thr
  // cover 32 rows/pass; 4 passes per 128-row panel; 8 gload/thread/tile.
  const int srow   = tid >> 3;                 // 0..31
  const int schunk = (tid & 7) ^ (srow & 7);   // pre-swizzled source chunk

  f32x4 acc[4][4];
  #pragma unroll
  for (int mi = 0; mi < 4; ++mi)
    #pragma unroll
    for (int ni = 0; ni < 4; ++ni)
      acc[mi][ni] = (f32x4){0.f, 0.f, 0.f, 0.f};

  for (int t = 0; t < NT; ++t){
    // ---- stage tile t (linear LDS dest, pre-swizzled global source) ----
    #pragma unroll
    for (int r_ = 0; r_ < 4; ++r_){
      const unsigned short* ga_ = gA + (size_t)(r_*32 + srow) * Dsz + t*BK + schunk*8;
      __builtin_amdgcn_global_load_lds(
        (const __attribute__((address_space(1))) unsigned int*)ga_,
        (__attribute__((address_space(3))) unsigned int*)&As[r_*2048 + wid*512], 16, 0, 0);
    }
    #pragma unroll
    for (int r_ = 0; r_ < 4; ++r_){
      const unsigned short* gb_ = gB + (size_t)(r_*32 + srow) * Dsz + t*BK + schunk*8;
      __builtin_amdgcn_global_load_lds(
        (const __attribute__((address_space(1))) unsigned int*)gb_,
        (__attribute__((address_space(3))) unsigned int*)&Bs[r_*2048 + wid*512], 16, 0, 0);
    }
    __syncthreads();   // compiler drains vmcnt before barrier -> tile ready

    // ---- compute: plain C++ reads, compiler-scheduled waits ----
    #pragma unroll
    for (int kk = 0; kk < 2; ++kk){
      bf16x8 av[4], bv[4];
      const int chunk = ((kk*4 + lhi) ^ (l15 & 7)) * 8;
      #pragma unroll
      for (int mi = 0; mi < 4; ++mi)
        av[mi] = *(const bf16x8*)&As[(wr*64 + mi*16 + l15)*64 + chunk];
      #pragma unroll
      for (int ni = 0; ni < 4; ++ni)
        bv[ni] = *(const bf16x8*)&Bs[(wc*64 + ni*16 + l15)*64 + chunk];
      #pragma unroll
      for (int mi = 0; mi < 4; ++mi)
        #pragma unroll
        for (int ni = 0; ni < 4; ++ni)
          acc[mi][ni] = __builtin_amdgcn_mfma_f32_16x16x32_bf16(av[mi], bv[ni], acc[mi][ni], 0, 0, 0);
    }
    __syncthreads();   // protect LDS before next stage overwrites
  }

  // ---- fused epilogue: d2 -> dist -> exp -> *W, then column-sum ----
  const int rowbase0 = bm * BM + wr * 64;
  f32x4 rs[4];
  #pragma unroll
  for (int mi = 0; mi < 4; ++mi) rs[mi] = (f32x4){0.f, 0.f, 0.f, 0.f};

  f32x4 x2r[4];
  #pragma unroll
  for (int mi = 0; mi < 4; ++mi)
    x2r[mi] = *(const f32x4*)&x2[rowbase0 + mi * 16 + lhi * 4];

  #pragma unroll
  for (int ni = 0; ni < 4; ++ni){
    const int col = bn * BN + wc * 64 + ni * 16 + l15;
    const float c2v = c2[col], bt = beta[col], wv = W[col];
    #pragma unroll
    for (int mi = 0; mi < 4; ++mi)
      #pragma unroll
      for (int j = 0; j < 4; ++j){
        float s    = acc[mi][ni][j];
        float d2   = x2r[mi][j] + c2v - 2.0f * s;
        float dist = sqrtf(fmaxf(d2, 0.0f));
        rs[mi][j] += wv * __expf(-bt * dist);   // exp(<=0) can't be inf
      }
  }

  // reduce over the 16 lanes holding different cols; write per-(bn,wc) partials
  const size_t pcbase = (size_t)(bn * 2 + wc) * Bsz;
  #pragma unroll
  for (int mi = 0; mi < 4; ++mi){
    #pragma unroll
    for (int j = 0; j < 4; ++j){
      float v = rs[mi][j];
      v += __shfl_xor(v, 1, 16);
      v += __shfl_xor(v, 2, 16);
      v += __shfl_xor(v, 4, 16);
      v += __shfl_xor(v, 8, 16);
      rs[mi][j] = v;
    }
    if (l15 == 0)
      *(f32x4*)&partials[pcbase + rowbase0 + mi * 16 + lhi * 4] = rs[mi];
  }
}

// ---------------- final reduction over column-groups ----------------
__global__ __launch_bounds__(256) void reduce_kernel(
    const float* __restrict__ partials, const float* __restrict__ bias,
    float* __restrict__ out)
{
  int b = blockIdx.x * 256 + threadIdx.x;
  float s = bias[0];
  #pragma unroll
  for (int t = 0; t < NPC; ++t) s += partials[(size_t)t * Bsz + b];
  out[b] = s;
}

// ---------------- naive f32 fallback (only if ws too small) ----------------
__global__ __launch_bounds__(256) void rbf_naive_kernel(
    const float* __restrict__ x, const float* __restrict__ cen,
    const float* __restrict__ beta, const float* __restrict__ W,
    const float* __restrict__ bias, float* __restrict__ out)
{
  __shared__ float4 xs4[Dsz / 4];
  __shared__ float red[256];
  int b = blockIdx.x;
  for (int i = threadIdx.x; i < Dsz / 4; i += 256)
    xs4[i] = ((const float4*)(x + (size_t)b * Dsz))[i];
  __syncthreads();
  float acc = 0.f;
  for (int j = threadIdx.x; j < Csz; j += 256){
    const float4* c4 = (const float4*)(cen + (size_t)j * Dsz);
    float d2 = 0.f;
    for (int k = 0; k < Dsz / 4; ++k){
      float4 cv = c4[k], xv = xs4[k];
      float a0 = xv.x - cv.x, a1 = xv.y - cv.y, a2 = xv.z - cv.z, a3 = xv.w - cv.w;
      d2 += a0*a0 + a1*a1 + a2*a2 + a3*a3;
    }
    acc += W[j] * expf(-beta[j] * sqrtf(fmaxf(d2, 0.f)));
  }
  red[threadIdx.x] = acc;
  __syncthreads();
  for (int s = 128; s >= 1; s >>= 1){
    if (threadIdx.x < s) red[threadIdx.x] += red[threadIdx.x + s];
    __syncthreads();
  }
  if (threadIdx.x == 0) out[b] = red[0] + bias[0];
}

extern "C" void kernel_launch(void* const* d_in, const int* in_sizes, int n_in,
                              void* d_out, int out_size, void* d_ws, size_t ws_size,
                              hipStream_t stream)
{
  const float* x    = (const float*)d_in[0];
  const float* cen  = (const float*)d_in[1];
  const float* beta = (const float*)d_in[2];
  const float* W    = (const float*)d_in[3];
  const float* bias = (const float*)d_in[4];
  float* out = (float*)d_out;

  const size_t off_xb = 0;
  const size_t off_cb = off_xb + (size_t)Bsz * Dsz * sizeof(unsigned short);
  const size_t off_x2 = off_cb + (size_t)Csz * Dsz * sizeof(unsigned short);
  const size_t off_c2 = off_x2 + (size_t)Bsz * sizeof(float);
  const size_t off_p  = off_c2 + (size_t)Csz * sizeof(float);
  const size_t need   = off_p  + (size_t)NPC * Bsz * sizeof(float);

  if (ws_size < need){
    rbf_naive_kernel<<<Bsz, 256, 0, stream>>>(x, cen, beta, W, bias, out);
    return;
  }

  char* ws = (char*)d_ws;
  unsigned short* xb = (unsigned short*)(ws + off_xb);
  unsigned short* cb = (unsigned short*)(ws + off_cb);
  float* x2 = (float*)(ws + off_x2);
  float* c2 = (float*)(ws + off_c2);
  float* pp = (float*)(ws + off_p);

  prep_kernel<<<(Bsz + Csz) / 4, 256, 0, stream>>>(x, cen, xb, cb, x2, c2);
  rbf_gemm_kernel<<<1024, 256, 0, stream>>>(xb, cb, x2, c2, beta, W, pp);
  reduce_kernel<<<Bsz / 256, 256, 0, stream>>>(pp, bias, out);
}